// Round 17
// baseline (3622.168 us; speedup 1.0000x reference)
//
#include <hip/hip_runtime.h>
#include <math.h>

#pragma clang fp contract(off)

typedef __attribute__((ext_vector_type(8)))  short bf16x8;
typedef __attribute__((ext_vector_type(16))) float f32x16;

static constexpr int NQ   = 8;
static constexpr int K    = 2048;
static constexpr int D    = 512;
static constexpr int B    = 32;
static constexpr int T    = 1500;
static constexpr int N    = B * T;       // 48000
static constexpr int TPB  = 64;          // points per block
static constexpr int NBLK = N / TPB;     // 750
static constexpr int NTHR = 512;         // 8 waves
static constexpr float WINDOW = 1e-3f;   // validated round 12 (same filter math)

static constexpr size_t OUT_Q    = 0;
static constexpr size_t OUT_IDX  = (size_t)B * D * T;              // 24,576,000
static constexpr size_t OUT_LOSS = OUT_IDX + (size_t)B * NQ * T;   // 24,960,000

static constexpr int WS_PART = 0;        // float idx: loss partials
static constexpr int WS_CC   = 16384;    // float idx: NQ*K norms (bytes 65536..131072)
static constexpr size_t WS_A_OFF   = 131072;                      // byte offset = end of cc
static constexpr size_t A_TILES_U4 = (size_t)NQ * 64 * 32 * 64;   // 1,048,576 (hi only)
static constexpr size_t WS_NEEDED  = WS_A_OFF + A_TILES_U4 * 16;  // ~16.9 MB

// ---- ||cb_k||^2 exactly as numpy pairwise np.sum(cb*cb, axis=1) ------------
__global__ void cc_kernel(const float* __restrict__ cb, float* __restrict__ ws) {
    int i = blockIdx.x * blockDim.x + threadIdx.x;
    if (i >= NQ * K) return;
    const float* row = cb + (size_t)i * D;
    float blk[4];
    for (int b4 = 0; b4 < 4; ++b4) {
        const float* p = row + b4 * 128;
        float r0 = p[0]*p[0], r1 = p[1]*p[1], r2 = p[2]*p[2], r3 = p[3]*p[3];
        float r4 = p[4]*p[4], r5 = p[5]*p[5], r6 = p[6]*p[6], r7 = p[7]*p[7];
        for (int j = 8; j < 128; j += 8) {
            r0 += p[j+0]*p[j+0]; r1 += p[j+1]*p[j+1];
            r2 += p[j+2]*p[j+2]; r3 += p[j+3]*p[j+3];
            r4 += p[j+4]*p[j+4]; r5 += p[j+5]*p[j+5];
            r6 += p[j+6]*p[j+6]; r7 += p[j+7]*p[j+7];
        }
        blk[b4] = ((r0 + r1) + (r2 + r3)) + ((r4 + r5) + (r6 + r7));
    }
    ws[WS_CC + i] = (blk[0] + blk[1]) + (blk[2] + blk[3]);
}

// ---- helpers ---------------------------------------------------------------
__device__ __forceinline__ unsigned sort_u32(float s) {
    unsigned u = __float_as_uint(s);
    return u ^ ((u >> 31) ? 0xFFFFFFFFu : 0x80000000u);
}
__device__ __forceinline__ unsigned pack_sk(float s, int k) {
    return (sort_u32(s) & 0xFFFFF800u) | (unsigned)k;
}
__device__ __forceinline__ float unpack_score(unsigned pkt) {
    unsigned u = pkt & 0xFFFFF800u;
    unsigned b = (u & 0x80000000u) ? (u ^ 0x80000000u) : ~u;
    return __uint_as_float(b);
}
__device__ __forceinline__ void ins3(unsigned &x1, unsigned &x2, unsigned &x3, unsigned v) {
    unsigned t2 = (x1 > v) ? x1 : v;  x1 = (x1 < v) ? x1 : v;
    unsigned t4 = (x2 > t2) ? x2 : t2; x2 = (x2 < t2) ? x2 : t2;
    x3 = (x3 < t4) ? x3 : t4;
}
// RNE f32->bf16 (hi word only)
__device__ __forceinline__ unsigned bf16h(float f) {
    unsigned u = __float_as_uint(f);
    return (u + (0x7FFFu + ((u >> 16) & 1u))) >> 16;
}

#define MFMA_(acc, Av, Bv) acc = __builtin_amdgcn_mfma_f32_32x32x16_bf16( \
    *(const bf16x8*)&(Av), *(const bf16x8*)&(Bv), acc, 0, 0, 0)

// ---- prep: bf16(hi) codebook in fragment-major tiles -----------------------
__global__ void prep_kernel(const float* __restrict__ cb, uint4* __restrict__ wsA) {
    const int t = blockIdx.x * blockDim.x + threadIdx.x;
    const int lane   = t & 63;
    const int dchunk = (t >> 6) & 31;
    const int rg     = (t >> 11) & 63;
    const int q      = t >> 17;
    const int row = (rg << 5) + (lane & 31);
    const int d0  = (dchunk << 4) + ((lane >> 5) << 3);
    const float* src = cb + ((size_t)q * K + row) * D + d0;
    const float4 f0 = *(const float4*)(src);
    const float4 f1 = *(const float4*)(src + 4);
    unsigned wv[4];
    wv[0] = bf16h(f0.x) | (bf16h(f0.y) << 16);
    wv[1] = bf16h(f0.z) | (bf16h(f0.w) << 16);
    wv[2] = bf16h(f1.x) | (bf16h(f1.y) << 16);
    wv[3] = bf16h(f1.z) | (bf16h(f1.w) << 16);
    wsA[t] = make_uint4(wv[0], wv[1], wv[2], wv[3]);
}

// A-chunk load: linear chunk c in [0,128): rg-pair=c>>5, dc=c&31; tail clamped
#define ALOAD(P, c) { \
    const int cc_ = (c) < 127 ? (c) : 127; \
    const uint4* b_ = Aq + ((size_t)(((w << 3) + ((cc_ >> 5) << 1)) << 11)) \
                         + ((cc_ & 31) << 6) + lane; \
    P##h0 = b_[0]; P##h1 = b_[2048]; }

// consume chunk: 4 MFMA (single bf16)
#define CONSUME(P, dc_) { \
    const uint4 bh0 = sh.b[dc_][lh][l31]; \
    const uint4 bh1 = sh.b[dc_][lh][32 + l31]; \
    MFMA_(c00, P##h0, bh0); MFMA_(c01, P##h0, bh1); \
    MFMA_(c10, P##h1, bh0); MFMA_(c11, P##h1, bh1); }

// ---- main fused 8-stage RVQ: residual lives in GLOBAL (out[OUT_Q], x-layout)
__global__ __launch_bounds__(NTHR, 1) void rvq_main(
    const float* __restrict__ x, const float* __restrict__ cb,
    float* __restrict__ out, float* __restrict__ ws)
{
    struct ShMem {
        uint4 b[32][2][64];                 // B image (bf16 hi) 64KB
    };
    __shared__ ShMem sh;                            // 64 KB
    __shared__ unsigned redc[8][3][TPB];            // 6 KB per-wave packed top3
    __shared__ unsigned long long redE[8][TPB];     // 4 KB finalize reduce
    __shared__ int   kstar[TPB];
    __shared__ float lossw[8];
    // total ~74.4 KB -> 2 blocks/CU

    const int tid  = threadIdx.x;
    const int w    = tid >> 6;
    const int lane = tid & 63;
    const int l31  = lane & 31, lh = lane >> 5;
    const int blk  = blockIdx.x;
    const int n0   = blk * TPB;

    const int n  = n0 + lane;
    const int bp = n / T;
    const int tp = n - bp * T;
    const size_t xbase = (size_t)bp * (D * T) + tp;   // point 'lane' base (x-layout)

    const uint4* __restrict__ wsA = (const uint4*)((const char*)ws + WS_A_OFF);
    float* __restrict__ rout = out + OUT_Q;           // residual storage (x-layout)

    for (int q = 0; q < NQ; ++q) {
        const float* __restrict__ cbq  = cb + (size_t)q * K * D;
        const float* __restrict__ ccq  = ws + WS_CC + q * K;
        const float* __restrict__ rsrc = q ? (const float*)rout : x;

        // ---- build B image (bf16 hi) from global residual ----
        #pragma unroll 1
        for (int j0 = 0; j0 < 64; j0 += 8) {
            float v[8];
            #pragma unroll
            for (int e = 0; e < 8; ++e)
                v[e] = rsrc[xbase + (size_t)((w << 6) + j0 + e) * T];
            unsigned hw[4];
            #pragma unroll
            for (int e2 = 0; e2 < 4; ++e2)
                hw[e2] = bf16h(v[2*e2]) | (bf16h(v[2*e2 + 1]) << 16);
            const int dg     = (w << 6) + j0;
            const int dchunk = dg >> 4;
            const int lhw    = (dg >> 3) & 1;
            sh.b[dchunk][lhw][lane] = make_uint4(hw[0], hw[1], hw[2], hw[3]);
        }
        __syncthreads();   // (1) B image visible

        // ---- filter: barrier-free MFMA GEMM, A global->reg, 4-deep prefetch ----
        unsigned t0a=~0u,t0b=~0u,t0c=~0u, t1a=~0u,t1b=~0u,t1c=~0u;
        const uint4* __restrict__ Aq = wsA + (size_t)q * (64 * 32 * 64);

        uint4 Pah0,Pah1, Pbh0,Pbh1, Pch0,Pch1, Pdh0,Pdh1;
        ALOAD(Pa, 0); ALOAD(Pb, 1); ALOAD(Pc, 2);

        #pragma unroll 1
        for (int nc = 0; nc < 4; ++nc) {
            const int c0 = nc << 5;
            f32x16 c00, c01, c10, c11;
            #pragma unroll
            for (int i = 0; i < 16; ++i) { c00[i]=0.f; c01[i]=0.f; c10[i]=0.f; c11[i]=0.f; }

            #pragma unroll 1
            for (int dcb = 0; dcb < 32; dcb += 4) {
                ALOAD(Pd, c0 + dcb + 3); CONSUME(Pa, dcb + 0);
                ALOAD(Pa, c0 + dcb + 4); CONSUME(Pb, dcb + 1);
                ALOAD(Pb, c0 + dcb + 5); CONSUME(Pc, dcb + 2);
                ALOAD(Pc, c0 + dcb + 6); CONSUME(Pd, dcb + 3);
            }
            // fold into running top3 (C layout: col=pt l&31, row=(i&3)+8*(i>>2)+4*lh)
            const int kb = (w << 8) + (nc << 6);
            #pragma unroll
            for (int i = 0; i < 16; ++i) {
                const int krow = (i & 3) + ((i >> 2) << 3) + (lh << 2);
                const float cc0 = ccq[kb + krow];
                const float cc1 = ccq[kb + 32 + krow];
                ins3(t0a,t0b,t0c, pack_sk(fmaf(-2.f, c00[i], cc0), kb + krow));
                ins3(t0a,t0b,t0c, pack_sk(fmaf(-2.f, c10[i], cc1), kb + 32 + krow));
                ins3(t1a,t1b,t1c, pack_sk(fmaf(-2.f, c01[i], cc0), kb + krow));
                ins3(t1a,t1b,t1c, pack_sk(fmaf(-2.f, c11[i], cc1), kb + 32 + krow));
            }
        }
        // merge lane-halves (l <-> l^32: same pts, complementary k-rows)
        {
            unsigned m;
            m=(unsigned)__shfl_xor((int)t0a,32); ins3(t0a,t0b,t0c,m);
            m=(unsigned)__shfl_xor((int)t0b,32); ins3(t0a,t0b,t0c,m);
            m=(unsigned)__shfl_xor((int)t0c,32); ins3(t0a,t0b,t0c,m);
            m=(unsigned)__shfl_xor((int)t1a,32); ins3(t1a,t1b,t1c,m);
            m=(unsigned)__shfl_xor((int)t1b,32); ins3(t1a,t1b,t1c,m);
            m=(unsigned)__shfl_xor((int)t1c,32); ins3(t1a,t1b,t1c,m);
        }
        if (lane < 32) { redc[w][0][lane]=t0a; redc[w][1][lane]=t0b; redc[w][2][lane]=t0c; }
        else           { redc[w][0][lane]=t1a; redc[w][1][lane]=t1b; redc[w][2][lane]=t1c; }
        __syncthreads();   // (2) candidates visible

        // ---- finalize: np-fp32 grid emulation, wave-parallel, r from global ----
        {
            const int p = lane;   // this thread's point (n = n0+lane, base = xbase)
            unsigned bvp = ~0u;
            #pragma unroll
            for (int ww = 0; ww < 8; ++ww)
                #pragma unroll
                for (int j = 0; j < 3; ++j) {
                    const unsigned pk = redc[ww][j][p];
                    bvp = (pk < bvp) ? pk : bvp;
                }
            const float bv = unpack_score(bvp);
            const unsigned uthr = (sort_u32(bv + WINDOW) & 0xFFFFF800u) | 0x7FFu;

            unsigned long long mypk = ~0ull;
            float xx = 0.f; bool havexx = false;
            #pragma unroll 1
            for (int j = 0; j < 3; ++j) {
                const unsigned pk = redc[w][j][p];
                if (pk <= uthr) {
                    if (!havexx) {
                        // xx = np pairwise fp32 sum of r*r (exact replica)
                        float C4[4];
                        #pragma unroll 1
                        for (int b4 = 0; b4 < 4; ++b4) {
                            const int base = b4 * 128;
                            float a0,a1,a2,a3,a4,a5,a6,a7;
                            {
                                float t0=rsrc[xbase+(size_t)(base+0)*T], t1=rsrc[xbase+(size_t)(base+1)*T];
                                float t2=rsrc[xbase+(size_t)(base+2)*T], t3=rsrc[xbase+(size_t)(base+3)*T];
                                float t4=rsrc[xbase+(size_t)(base+4)*T], t5=rsrc[xbase+(size_t)(base+5)*T];
                                float t6=rsrc[xbase+(size_t)(base+6)*T], t7=rsrc[xbase+(size_t)(base+7)*T];
                                a0=t0*t0; a1=t1*t1; a2=t2*t2; a3=t3*t3;
                                a4=t4*t4; a5=t5*t5; a6=t6*t6; a7=t7*t7;
                            }
                            #pragma unroll 4
                            for (int jj = 8; jj < 128; jj += 8) {
                                float t0=rsrc[xbase+(size_t)(base+jj+0)*T], t1=rsrc[xbase+(size_t)(base+jj+1)*T];
                                float t2=rsrc[xbase+(size_t)(base+jj+2)*T], t3=rsrc[xbase+(size_t)(base+jj+3)*T];
                                float t4=rsrc[xbase+(size_t)(base+jj+4)*T], t5=rsrc[xbase+(size_t)(base+jj+5)*T];
                                float t6=rsrc[xbase+(size_t)(base+jj+6)*T], t7=rsrc[xbase+(size_t)(base+jj+7)*T];
                                a0+=t0*t0; a1+=t1*t1; a2+=t2*t2; a3+=t3*t3;
                                a4+=t4*t4; a5+=t5*t5; a6+=t6*t6; a7+=t7*t7;
                            }
                            C4[b4] = ((a0+a1)+(a2+a3)) + ((a4+a5)+(a6+a7));
                        }
                        xx = (C4[0] + C4[1]) + (C4[2] + C4[3]);
                        havexx = true;
                    }
                    const int kk = (int)(pk & 0x7FFu);
                    const float* crow = cbq + (size_t)kk * D;
                    float mm = 0.f;   // BLAS-chain fp32 dot, d-ascending fmaf
                    #pragma unroll 4
                    for (int d = 0; d < D; d += 4) {
                        const float4 c = *(const float4*)(crow + d);
                        mm = fmaf(c.x, rsrc[xbase+(size_t)(d+0)*T], mm);
                        mm = fmaf(c.y, rsrc[xbase+(size_t)(d+1)*T], mm);
                        mm = fmaf(c.z, rsrc[xbase+(size_t)(d+2)*T], mm);
                        mm = fmaf(c.w, rsrc[xbase+(size_t)(d+3)*T], mm);
                    }
                    const float D1 = xx - 2.0f * mm;   // fp32 round
                    const float E  = D1 + ccq[kk];     // fp32 round
                    const unsigned long long cand =
                        ((unsigned long long)sort_u32(E) << 32) | (unsigned)kk;
                    mypk = (cand < mypk) ? cand : mypk;
                }
            }
            redE[w][p] = mypk;
        }
        __syncthreads();   // (3) candidates evaluated

        if (tid < TPB) {
            const int p = tid;
            unsigned long long m = ~0ull;
            #pragma unroll
            for (int ww = 0; ww < 8; ++ww) {
                const unsigned long long v = redE[ww][p];
                m = (v < m) ? v : m;
            }
            const int bk = (int)(m & 0x7FFu);
            kstar[p] = bk;
            const int nn = n0 + p;
            const int b2 = nn / T;
            const int t2 = nn - b2 * T;
            out[OUT_IDX + (size_t)b2 * (NQ * T) + (size_t)q * T + t2] = (float)bk;
        }
        __syncthreads();   // (4) kstar ready

        // ---- residual update (exact elementwise fp32 sequence), global r ----
        {
            const int kp = kstar[lane];
            const float* __restrict__ crow = cbq + (size_t)kp * D + (w << 6);
            float part = 0.f;
            #pragma unroll 2
            for (int j4 = 0; j4 < 16; ++j4) {
                const float4 c = ((const float4*)crow)[j4];
                const size_t a0i = xbase + (size_t)((w << 6) + 4*j4) * T;
                float rv, aa, q0;
                rv = rsrc[a0i + 0*T]; aa = c.x - rv; q0 = rv + aa; rout[a0i + 0*T] = rv - q0; part = fmaf(aa,aa,part);
                rv = rsrc[a0i + 1*T]; aa = c.y - rv; q0 = rv + aa; rout[a0i + 1*T] = rv - q0; part = fmaf(aa,aa,part);
                rv = rsrc[a0i + 2*T]; aa = c.z - rv; q0 = rv + aa; rout[a0i + 2*T] = rv - q0; part = fmaf(aa,aa,part);
                rv = rsrc[a0i + 3*T]; aa = c.w - rv; q0 = rv + aa; rout[a0i + 3*T] = rv - q0; part = fmaf(aa,aa,part);
            }
            #pragma unroll
            for (int off = 32; off > 0; off >>= 1) part += __shfl_down(part, off);
            if (lane == 0) lossw[w] = part;
        }
        __syncthreads();   // (5) r updated + lossw ready (vmcnt drained by barrier)
        if (tid == 0) {
            float s = 0.f;
            #pragma unroll
            for (int ww = 0; ww < 8; ++ww) s += lossw[ww];
            ws[WS_PART + q * NBLK + blk] = s;
        }
        __syncthreads();   // (6) safe to rebuild B image next stage
    }
}

// ---- quantized_out = x - r (in place over the r storage) -------------------
__global__ void quant_kernel(const float* __restrict__ x, float* __restrict__ out) {
    const size_t total = (size_t)B * D * T / 4;
    for (size_t i = blockIdx.x * blockDim.x + threadIdx.x; i < total;
         i += (size_t)gridDim.x * blockDim.x) {
        const float4 xv = ((const float4*)x)[i];
        const float4 rv = ((const float4*)(out + OUT_Q))[i];
        ((float4*)(out + OUT_Q))[i] =
            make_float4(xv.x - rv.x, xv.y - rv.y, xv.z - rv.z, xv.w - rv.w);
    }
}

// ================= fallback (round-5 verified kernel, 64 pts/block) =========
static constexpr int FB_TPB = 64;
static constexpr int FB_NBLK = N / FB_TPB;   // 750
static constexpr int KT  = 32;
static constexpr int DC  = 16;
static constexpr int KPW = 256;
static constexpr int TOPC = 3;
static constexpr float FBWIN = 3e-4f;

__global__ __launch_bounds__(NTHR) void rvq_fallback(
    const float* __restrict__ x, const float* __restrict__ cb,
    float* __restrict__ out, float* __restrict__ ws)
{
    __shared__ float r[D][FB_TPB];
    __shared__ float cbc[8][KT][DC];
    __shared__ float redv[8][TOPC][FB_TPB];
    __shared__ int   redi[8][TOPC][FB_TPB];
    __shared__ int   kstar[FB_TPB];
    __shared__ float lossw[8];

    const int tid  = threadIdx.x;
    const int w    = tid >> 6;
    const int lane = tid & 63;
    const int blk  = blockIdx.x;
    const int n0   = blk * FB_TPB;

    const int n  = n0 + lane;
    const int bp = n / T;
    const int tp = n - bp * T;
    const size_t xbase = (size_t)bp * (D * T) + tp;

    for (int j = 0; j < 64; ++j) {
        const int d = (w << 6) + j;
        r[d][lane] = x[xbase + (size_t)d * T];
    }
    __syncthreads();

    const int kw0  = w * KPW;
    const int lrow = lane >> 2;
    const int lcol = (lane & 3) << 2;

    for (int q = 0; q < NQ; ++q) {
        const float* __restrict__ cbq = cb + (size_t)q * K * D;
        const float* __restrict__ ccq = ws + WS_CC + q * K;

        float v1 = 3.0e38f, v2 = 3.0e38f, v3 = 3.0e38f;
        int   i1 = 0,       i2 = 0,       i3 = 0;
        float4 pf0, pf1;
        {
            const float* s0 = cbq + (size_t)(kw0 + lrow) * D + lcol;
            pf0 = *(const float4*)(s0);
            pf1 = *(const float4*)(s0 + 16 * D);
        }
        #pragma unroll 1
        for (int kc = 0; kc < KPW / KT; ++kc) {
            const int k0 = kw0 + kc * KT;
            float acc[KT];
            #pragma unroll
            for (int kk = 0; kk < KT; ++kk) acc[kk] = 0.f;
            #pragma unroll 1
            for (int dc = 0; dc < D / DC; ++dc) {
                asm volatile("s_waitcnt lgkmcnt(0)" ::: "memory");
                ((float4*)&cbc[w][0][0])[lane]      = pf0;
                ((float4*)&cbc[w][0][0])[lane + 64] = pf1;
                {
                    int nkc = kc, ndc = dc + 1;
                    if (ndc == D / DC) { ndc = 0; nkc++; }
                    if (nkc < KPW / KT) {
                        const float* s0 = cbq + (size_t)(kw0 + nkc * KT + lrow) * D
                                              + ndc * DC + lcol;
                        pf0 = *(const float4*)(s0);
                        pf1 = *(const float4*)(s0 + 16 * D);
                    }
                }
                asm volatile("s_waitcnt lgkmcnt(0)" ::: "memory");
                const int d0 = dc * DC;
                #pragma unroll
                for (int dd = 0; dd < DC; dd += 4) {
                    const float r0 = r[d0 + dd + 0][lane];
                    const float r1 = r[d0 + dd + 1][lane];
                    const float r2 = r[d0 + dd + 2][lane];
                    const float r3 = r[d0 + dd + 3][lane];
                    #pragma unroll
                    for (int kk = 0; kk < KT; ++kk) {
                        const float4 c = *(const float4*)&cbc[w][kk][dd];
                        acc[kk] = fmaf(c.x, r0, acc[kk]);
                        acc[kk] = fmaf(c.y, r1, acc[kk]);
                        acc[kk] = fmaf(c.z, r2, acc[kk]);
                        acc[kk] = fmaf(c.w, r3, acc[kk]);
                    }
                }
            }
            #pragma unroll
            for (int kk = 0; kk < KT; ++kk) {
                const float s = fmaf(-2.f, acc[kk], ccq[k0 + kk]);
                if (s < v1)      { v3 = v2; i3 = i2; v2 = v1; i2 = i1; v1 = s; i1 = k0 + kk; }
                else if (s < v2) { v3 = v2; i3 = i2; v2 = s;  i2 = k0 + kk; }
                else if (s < v3) { v3 = s;  i3 = k0 + kk; }
            }
        }
        redv[w][0][lane] = v1; redi[w][0][lane] = i1;
        redv[w][1][lane] = v2; redi[w][1][lane] = i2;
        redv[w][2][lane] = v3; redi[w][2][lane] = i3;
        __syncthreads();

        if (tid < FB_TPB) {
            const int p = tid;
            float C4[4];
            #pragma unroll 1
            for (int b4 = 0; b4 < 4; ++b4) {
                const int base = b4 * 128;
                float a0,a1,a2,a3,a4,a5,a6,a7;
                {
                    float t0=r[base+0][p], t1=r[base+1][p], t2=r[base+2][p], t3=r[base+3][p];
                    float t4=r[base+4][p], t5=r[base+5][p], t6=r[base+6][p], t7=r[base+7][p];
                    a0=t0*t0; a1=t1*t1; a2=t2*t2; a3=t3*t3;
                    a4=t4*t4; a5=t5*t5; a6=t6*t6; a7=t7*t7;
                }
                for (int j = 8; j < 128; j += 8) {
                    float t0=r[base+j+0][p], t1=r[base+j+1][p];
                    float t2=r[base+j+2][p], t3=r[base+j+3][p];
                    float t4=r[base+j+4][p], t5=r[base+j+5][p];
                    float t6=r[base+j+6][p], t7=r[base+j+7][p];
                    a0+=t0*t0; a1+=t1*t1; a2+=t2*t2; a3+=t3*t3;
                    a4+=t4*t4; a5+=t5*t5; a6+=t6*t6; a7+=t7*t7;
                }
                C4[b4] = ((a0+a1)+(a2+a3)) + ((a4+a5)+(a6+a7));
            }
            const float xx = (C4[0] + C4[1]) + (C4[2] + C4[3]);

            float bv = 3.0e38f;
            #pragma unroll
            for (int ww = 0; ww < 8; ++ww)
                #pragma unroll
                for (int j = 0; j < TOPC; ++j) {
                    const float v = redv[ww][j][p];
                    if (v < bv) bv = v;
                }
            float bestE = 3.0e38f; int bestK = 0x7fffffff;
            #pragma unroll 1
            for (int ww = 0; ww < 8; ++ww)
                #pragma unroll 1
                for (int j = 0; j < TOPC; ++j) {
                    const float v = redv[ww][j][p];
                    const int  kk = redi[ww][j][p];
                    if (v <= bv + FBWIN) {
                        const float* crow = cbq + (size_t)kk * D;
                        float mm = 0.f;
                        #pragma unroll 1
                        for (int d = 0; d < D; d += 4) {
                            const float4 c = *(const float4*)(crow + d);
                            mm = fmaf(c.x, r[d+0][p], mm);
                            mm = fmaf(c.y, r[d+1][p], mm);
                            mm = fmaf(c.z, r[d+2][p], mm);
                            mm = fmaf(c.w, r[d+3][p], mm);
                        }
                        const float D1 = xx - 2.0f * mm;
                        const float E  = D1 + ccq[kk];
                        if (E < bestE || (E == bestE && kk < bestK)) { bestE = E; bestK = kk; }
                    }
                }
            kstar[p] = bestK;
            const int nn = n0 + p;
            const int b2 = nn / T;
            const int t2 = nn - b2 * T;
            out[OUT_IDX + (size_t)b2 * (NQ * T) + (size_t)q * T + t2] = (float)bestK;
        }
        __syncthreads();

        {
            const int kp = kstar[lane];
            const float* __restrict__ crow = cbq + (size_t)kp * D;
            float part = 0.f;
            #pragma unroll 1
            for (int j = 0; j < 64; j += 4) {
                const int d = (w << 6) + j;
                const float4 c = *(const float4*)(crow + d);
                float rv0 = r[d + 0][lane], rv1 = r[d + 1][lane];
                float rv2 = r[d + 2][lane], rv3 = r[d + 3][lane];
                float a0 = c.x - rv0, a1 = c.y - rv1;
                float a2 = c.z - rv2, a3 = c.w - rv3;
                float q0 = rv0 + a0, q1 = rv1 + a1;
                float q2 = rv2 + a2, q3 = rv3 + a3;
                r[d + 0][lane] = rv0 - q0; r[d + 1][lane] = rv1 - q1;
                r[d + 2][lane] = rv2 - q2; r[d + 3][lane] = rv3 - q3;
                part = fmaf(a0, a0, part); part = fmaf(a1, a1, part);
                part = fmaf(a2, a2, part); part = fmaf(a3, a3, part);
            }
            #pragma unroll
            for (int off = 32; off > 0; off >>= 1) part += __shfl_down(part, off);
            if (lane == 0) lossw[w] = part;
        }
        __syncthreads();
        if (tid == 0) {
            float s = 0.f;
            #pragma unroll
            for (int ww = 0; ww < 8; ++ww) s += lossw[ww];
            ws[WS_PART + q * FB_NBLK + blk] = s;
        }
        __syncthreads();
    }

    for (int j = 0; j < 64; ++j) {
        const int d = (w << 6) + j;
        const size_t a = xbase + (size_t)d * T;
        out[OUT_Q + a] = x[a] - r[d][lane];
    }
}

// ---- deterministic loss finalize ------------------------------------------
__global__ void loss_kernel(const float* __restrict__ ws, float* __restrict__ out,
                            int npart) {
    __shared__ double s[256];
    double acc = 0.0;
    for (int i = threadIdx.x; i < npart; i += 256) acc += (double)ws[WS_PART + i];
    s[threadIdx.x] = acc;
    __syncthreads();
    for (int o = 128; o > 0; o >>= 1) {
        if ((int)threadIdx.x < o) s[threadIdx.x] += s[threadIdx.x + o];
        __syncthreads();
    }
    if (threadIdx.x == 0)
        out[OUT_LOSS] = (float)(s[0] / (double)((size_t)B * D * T));
}

extern "C" void kernel_launch(void* const* d_in, const int* in_sizes, int n_in,
                              void* d_out, int out_size, void* d_ws, size_t ws_size,
                              hipStream_t stream) {
    const float* x  = (const float*)d_in[0];
    const float* cb = (const float*)d_in[1];
    float* out = (float*)d_out;
    float* ws  = (float*)d_ws;

    hipLaunchKernelGGL(cc_kernel, dim3((NQ * K + 255) / 256), dim3(256), 0, stream, cb, ws);
    if (ws_size >= WS_NEEDED) {
        uint4* wsA = (uint4*)((char*)d_ws + WS_A_OFF);
        hipLaunchKernelGGL(prep_kernel, dim3((unsigned)(A_TILES_U4 / 256)), dim3(256),
                           0, stream, cb, wsA);
        hipLaunchKernelGGL(rvq_main, dim3(NBLK), dim3(NTHR), 0, stream, x, cb, out, ws);
        hipLaunchKernelGGL(quant_kernel, dim3(2048), dim3(256), 0, stream, x, out);
        hipLaunchKernelGGL(loss_kernel, dim3(1), dim3(256), 0, stream, ws, out,
                           NQ * NBLK);
    } else {
        hipLaunchKernelGGL(rvq_fallback, dim3(FB_NBLK), dim3(NTHR), 0, stream, x, cb, out, ws);
        hipLaunchKernelGGL(loss_kernel, dim3(1), dim3(256), 0, stream, ws, out,
                           NQ * FB_NBLK);
    }
}

// Round 18
// 1973.633 us; speedup vs baseline: 1.8353x; 1.8353x over previous
//
#include <hip/hip_runtime.h>
#include <math.h>

#pragma clang fp contract(off)

typedef __attribute__((ext_vector_type(8)))  short bf16x8;
typedef __attribute__((ext_vector_type(16))) float f32x16;

static constexpr int NQ   = 8;
static constexpr int K    = 2048;
static constexpr int D    = 512;
static constexpr int B    = 32;
static constexpr int T    = 1500;
static constexpr int N    = B * T;       // 48000
static constexpr int TPB  = 64;          // points per block
static constexpr int NBLK = N / TPB;     // 750
static constexpr int NTHR = 512;         // 8 waves
static constexpr float WINDOW = 1e-3f;   // validated round 12 (same filter math)

static constexpr size_t OUT_Q    = 0;
static constexpr size_t OUT_IDX  = (size_t)B * D * T;              // 24,576,000
static constexpr size_t OUT_LOSS = OUT_IDX + (size_t)B * NQ * T;   // 24,960,000

static constexpr int WS_PART = 0;        // float idx: loss partials
static constexpr int WS_CC   = 16384;    // float idx: NQ*K norms (bytes 65536..131072)
static constexpr size_t WS_A_OFF   = 131072;                      // byte offset = end of cc
static constexpr size_t A_TILES_U4 = (size_t)NQ * 64 * 32 * 64;   // 1,048,576 (hi only)
static constexpr size_t WS_NEEDED  = WS_A_OFF + A_TILES_U4 * 16;  // ~16.9 MB

// ---- ||cb_k||^2 exactly as numpy pairwise np.sum(cb*cb, axis=1) ------------
__global__ void cc_kernel(const float* __restrict__ cb, float* __restrict__ ws) {
    int i = blockIdx.x * blockDim.x + threadIdx.x;
    if (i >= NQ * K) return;
    const float* row = cb + (size_t)i * D;
    float blk[4];
    for (int b4 = 0; b4 < 4; ++b4) {
        const float* p = row + b4 * 128;
        float r0 = p[0]*p[0], r1 = p[1]*p[1], r2 = p[2]*p[2], r3 = p[3]*p[3];
        float r4 = p[4]*p[4], r5 = p[5]*p[5], r6 = p[6]*p[6], r7 = p[7]*p[7];
        for (int j = 8; j < 128; j += 8) {
            r0 += p[j+0]*p[j+0]; r1 += p[j+1]*p[j+1];
            r2 += p[j+2]*p[j+2]; r3 += p[j+3]*p[j+3];
            r4 += p[j+4]*p[j+4]; r5 += p[j+5]*p[j+5];
            r6 += p[j+6]*p[j+6]; r7 += p[j+7]*p[j+7];
        }
        blk[b4] = ((r0 + r1) + (r2 + r3)) + ((r4 + r5) + (r6 + r7));
    }
    ws[WS_CC + i] = (blk[0] + blk[1]) + (blk[2] + blk[3]);
}

// ---- helpers ---------------------------------------------------------------
__device__ __forceinline__ unsigned sort_u32(float s) {
    unsigned u = __float_as_uint(s);
    return u ^ ((u >> 31) ? 0xFFFFFFFFu : 0x80000000u);
}
__device__ __forceinline__ unsigned pack_sk(float s, int k) {
    return (sort_u32(s) & 0xFFFFF800u) | (unsigned)k;
}
__device__ __forceinline__ float unpack_score(unsigned pkt) {
    unsigned u = pkt & 0xFFFFF800u;
    unsigned b = (u & 0x80000000u) ? (u ^ 0x80000000u) : ~u;
    return __uint_as_float(b);
}
__device__ __forceinline__ void ins3(unsigned &x1, unsigned &x2, unsigned &x3, unsigned v) {
    unsigned t2 = (x1 > v) ? x1 : v;  x1 = (x1 < v) ? x1 : v;
    unsigned t4 = (x2 > t2) ? x2 : t2; x2 = (x2 < t2) ? x2 : t2;
    x3 = (x3 < t4) ? x3 : t4;
}
// RNE f32->bf16 (hi word only)
__device__ __forceinline__ unsigned bf16h(float f) {
    unsigned u = __float_as_uint(f);
    return (u + (0x7FFFu + ((u >> 16) & 1u))) >> 16;
}

#define MFMA_(acc, Av, Bv) acc = __builtin_amdgcn_mfma_f32_32x32x16_bf16( \
    *(const bf16x8*)&(Av), *(const bf16x8*)&(Bv), acc, 0, 0, 0)

// ---- prep: bf16(hi) codebook in fragment-major tiles -----------------------
// tile (q, rg[64], dchunk[32]) = 64 lanes x uint4 : lane l holds
// row rg*32+(l&31), d = dchunk*16 + (l>>5)*8 + 0..7 (2 bf16 per u32, low=even d)
__global__ void prep_kernel(const float* __restrict__ cb, uint4* __restrict__ wsA) {
    const int t = blockIdx.x * blockDim.x + threadIdx.x;
    const int lane   = t & 63;
    const int dchunk = (t >> 6) & 31;
    const int rg     = (t >> 11) & 63;
    const int q      = t >> 17;
    const int row = (rg << 5) + (lane & 31);
    const int d0  = (dchunk << 4) + ((lane >> 5) << 3);
    const float* src = cb + ((size_t)q * K + row) * D + d0;
    const float4 f0 = *(const float4*)(src);
    const float4 f1 = *(const float4*)(src + 4);
    unsigned wv[4];
    wv[0] = bf16h(f0.x) | (bf16h(f0.y) << 16);
    wv[1] = bf16h(f0.z) | (bf16h(f0.w) << 16);
    wv[2] = bf16h(f1.x) | (bf16h(f1.y) << 16);
    wv[3] = bf16h(f1.z) | (bf16h(f1.w) << 16);
    wsA[t] = make_uint4(wv[0], wv[1], wv[2], wv[3]);
}

// A-chunk load: linear chunk c in [0,128): rg-pair=c>>5, dc=c&31; tail clamped
#define ALOAD(P, c) { \
    const int cc_ = (c) < 127 ? (c) : 127; \
    const uint4* b_ = Aq + ((size_t)(((w << 3) + ((cc_ >> 5) << 1)) << 11)) \
                         + ((cc_ & 31) << 6) + lane; \
    P##h0 = b_[0]; P##h1 = b_[2048]; }

// consume chunk: 4 MFMA (single bf16)
#define CONSUME(P, dc_) { \
    const uint4 bh0 = sh.f.b[dc_][lh][l31]; \
    const uint4 bh1 = sh.f.b[dc_][lh][32 + l31]; \
    MFMA_(c00, P##h0, bh0); MFMA_(c01, P##h0, bh1); \
    MFMA_(c10, P##h1, bh0); MFMA_(c11, P##h1, bh1); }

// ---- main fused 8-stage RVQ ------------------------------------------------
__global__ __launch_bounds__(NTHR, 1) void rvq_main(
    const float* __restrict__ x, const float* __restrict__ cb,
    float* __restrict__ out, float* __restrict__ ws)
{
    union ShMem {
        struct { uint4 b[32][2][64]; } f;       // B image (hi) [dchunk][lhw][pt] 64KB
        float dump[TPB][D + 4];                 // fp32 residual, padded rows 132KB
    };
    __shared__ ShMem sh;
    __shared__ float ccs[K];                       // 8 KB
    __shared__ unsigned redc[8][3][TPB];           // 6 KB per-wave packed top3
    __shared__ unsigned long long redE[8][TPB];    // 4 KB finalize reduce
    __shared__ int   kstar[TPB];
    __shared__ float lossw[8];

    const int tid  = threadIdx.x;
    const int w    = tid >> 6;
    const int lane = tid & 63;
    const int l31  = lane & 31, lh = lane >> 5;
    const int blk  = blockIdx.x;
    const int n0   = blk * TPB;

    const int n  = n0 + lane;
    const int bp = n / T;
    const int tp = n - bp * T;
    const size_t xbase = (size_t)bp * (D * T) + tp;

    const uint4* __restrict__ wsA = (const uint4*)((const char*)ws + WS_A_OFF);

    // residual in registers: rr[j] = r[w*64+j][point=lane]
    float rr[64];
    #pragma unroll
    for (int j = 0; j < 64; ++j) rr[j] = x[xbase + (size_t)((w << 6) + j) * T];

    for (int q = 0; q < NQ; ++q) {
        const float* __restrict__ cbq = cb + (size_t)q * K * D;
        const float* __restrict__ ccq = ws + WS_CC + q * K;
        for (int i = tid; i < K; i += NTHR) ccs[i] = ccq[i];

        // ---- build B image (bf16 hi, once per stage) ----
        #pragma unroll
        for (int j0 = 0; j0 < 64; j0 += 8) {
            unsigned hw[4];
            #pragma unroll
            for (int e2 = 0; e2 < 4; ++e2)
                hw[e2] = bf16h(rr[j0 + 2*e2]) | (bf16h(rr[j0 + 2*e2 + 1]) << 16);
            const int dg     = (w << 6) + j0;
            const int dchunk = dg >> 4;
            const int lhw    = (dg >> 3) & 1;
            sh.f.b[dchunk][lhw][lane] = make_uint4(hw[0], hw[1], hw[2], hw[3]);
        }
        __syncthreads();   // (1) B image + ccs visible

        // ---- filter: barrier-free MFMA GEMM, A global->reg, 4-deep prefetch ----
        unsigned t0a=~0u,t0b=~0u,t0c=~0u, t1a=~0u,t1b=~0u,t1c=~0u;
        const uint4* __restrict__ Aq = wsA + (size_t)q * (64 * 32 * 64);

        uint4 Pah0,Pah1, Pbh0,Pbh1, Pch0,Pch1, Pdh0,Pdh1;
        ALOAD(Pa, 0); ALOAD(Pb, 1); ALOAD(Pc, 2);

        #pragma unroll 1
        for (int nc = 0; nc < 4; ++nc) {
            const int c0 = nc << 5;
            f32x16 c00, c01, c10, c11;
            #pragma unroll
            for (int i = 0; i < 16; ++i) { c00[i]=0.f; c01[i]=0.f; c10[i]=0.f; c11[i]=0.f; }

            #pragma unroll 1
            for (int dcb = 0; dcb < 32; dcb += 4) {
                ALOAD(Pd, c0 + dcb + 3); CONSUME(Pa, dcb + 0);
                ALOAD(Pa, c0 + dcb + 4); CONSUME(Pb, dcb + 1);
                ALOAD(Pb, c0 + dcb + 5); CONSUME(Pc, dcb + 2);
                ALOAD(Pc, c0 + dcb + 6); CONSUME(Pd, dcb + 3);
            }
            // fold into running top3 (C layout: col=pt l&31, row=(i&3)+8*(i>>2)+4*lh)
            const int kb = (w << 8) + (nc << 6);
            #pragma unroll
            for (int i = 0; i < 16; ++i) {
                const int krow = (i & 3) + ((i >> 2) << 3) + (lh << 2);
                const float cc0 = ccs[kb + krow];
                const float cc1 = ccs[kb + 32 + krow];
                ins3(t0a,t0b,t0c, pack_sk(fmaf(-2.f, c00[i], cc0), kb + krow));
                ins3(t0a,t0b,t0c, pack_sk(fmaf(-2.f, c10[i], cc1), kb + 32 + krow));
                ins3(t1a,t1b,t1c, pack_sk(fmaf(-2.f, c01[i], cc0), kb + krow));
                ins3(t1a,t1b,t1c, pack_sk(fmaf(-2.f, c11[i], cc1), kb + 32 + krow));
            }
        }
        // merge lane-halves (l <-> l^32: same pts, complementary k-rows)
        {
            unsigned m;
            m=(unsigned)__shfl_xor((int)t0a,32); ins3(t0a,t0b,t0c,m);
            m=(unsigned)__shfl_xor((int)t0b,32); ins3(t0a,t0b,t0c,m);
            m=(unsigned)__shfl_xor((int)t0c,32); ins3(t0a,t0b,t0c,m);
            m=(unsigned)__shfl_xor((int)t1a,32); ins3(t1a,t1b,t1c,m);
            m=(unsigned)__shfl_xor((int)t1b,32); ins3(t1a,t1b,t1c,m);
            m=(unsigned)__shfl_xor((int)t1c,32); ins3(t1a,t1b,t1c,m);
        }
        if (lane < 32) { redc[w][0][lane]=t0a; redc[w][1][lane]=t0b; redc[w][2][lane]=t0c; }
        else           { redc[w][0][lane]=t1a; redc[w][1][lane]=t1b; redc[w][2][lane]=t1c; }
        __syncthreads();   // (2) filter done; B image dead

        // ---- dump residual [pt][d] (padded) for exact finalize ----
        #pragma unroll
        for (int j0 = 0; j0 < 64; j0 += 4)
            *(float4*)&sh.dump[lane][(w << 6) + j0] =
                make_float4(rr[j0], rr[j0+1], rr[j0+2], rr[j0+3]);
        __syncthreads();   // (3) dump visible

        // ---- finalize: np-fp32 grid emulation, wave-parallel ----
        {
            const int p = lane;
            unsigned bvp = ~0u;
            #pragma unroll
            for (int ww = 0; ww < 8; ++ww)
                #pragma unroll
                for (int j = 0; j < 3; ++j) {
                    const unsigned pk = redc[ww][j][p];
                    bvp = (pk < bvp) ? pk : bvp;
                }
            const float bv = unpack_score(bvp);
            const unsigned uthr = (sort_u32(bv + WINDOW) & 0xFFFFF800u) | 0x7FFu;

            unsigned long long mypk = ~0ull;
            float xx = 0.f; bool havexx = false;
            #pragma unroll 1
            for (int j = 0; j < 3; ++j) {
                const unsigned pk = redc[w][j][p];
                if (pk <= uthr) {
                    if (!havexx) {
                        // xx = np pairwise fp32 sum of r*r (exact replica)
                        float C4[4];
                        #pragma unroll 1
                        for (int b4 = 0; b4 < 4; ++b4) {
                            const int base = b4 * 128;
                            float4 u = *(const float4*)&sh.dump[p][base];
                            float4 v = *(const float4*)&sh.dump[p][base + 4];
                            float a0=u.x*u.x, a1=u.y*u.y, a2=u.z*u.z, a3=u.w*u.w;
                            float a4=v.x*v.x, a5=v.y*v.y, a6=v.z*v.z, a7=v.w*v.w;
                            for (int jj = 8; jj < 128; jj += 8) {
                                u = *(const float4*)&sh.dump[p][base + jj];
                                v = *(const float4*)&sh.dump[p][base + jj + 4];
                                a0+=u.x*u.x; a1+=u.y*u.y; a2+=u.z*u.z; a3+=u.w*u.w;
                                a4+=v.x*v.x; a5+=v.y*v.y; a6+=v.z*v.z; a7+=v.w*v.w;
                            }
                            C4[b4] = ((a0+a1)+(a2+a3)) + ((a4+a5)+(a6+a7));
                        }
                        xx = (C4[0] + C4[1]) + (C4[2] + C4[3]);
                        havexx = true;
                    }
                    const int kk = (int)(pk & 0x7FFu);
                    const float* crow = cbq + (size_t)kk * D;
                    float mm = 0.f;   // BLAS-chain fp32 dot, d-ascending fmaf
                    #pragma unroll 1
                    for (int d = 0; d < D; d += 4) {
                        const float4 c  = *(const float4*)(crow + d);
                        const float4 rv = *(const float4*)&sh.dump[p][d];
                        mm = fmaf(c.x, rv.x, mm);
                        mm = fmaf(c.y, rv.y, mm);
                        mm = fmaf(c.z, rv.z, mm);
                        mm = fmaf(c.w, rv.w, mm);
                    }
                    const float D1 = xx - 2.0f * mm;   // fp32 round
                    const float E  = D1 + ccs[kk];     // fp32 round
                    const unsigned long long cand =
                        ((unsigned long long)sort_u32(E) << 32) | (unsigned)kk;
                    mypk = (cand < mypk) ? cand : mypk;
                }
            }
            redE[w][p] = mypk;
        }
        __syncthreads();   // (4) candidates evaluated

        if (tid < TPB) {
            const int p = tid;
            unsigned long long m = ~0ull;
            #pragma unroll
            for (int ww = 0; ww < 8; ++ww) {
                const unsigned long long v = redE[ww][p];
                m = (v < m) ? v : m;
            }
            const int bk = (int)(m & 0x7FFu);
            kstar[p] = bk;
            const int nn = n0 + p;
            const int b2 = nn / T;
            const int t2 = nn - b2 * T;
            out[OUT_IDX + (size_t)b2 * (NQ * T) + (size_t)q * T + t2] = (float)bk;
        }
        __syncthreads();   // (5) kstar ready

        // ---- residual update (exact elementwise fp32 sequence) ----
        {
            const int kp = kstar[lane];
            const float* __restrict__ crow = cbq + (size_t)kp * D + (w << 6);
            float part = 0.f;
            #pragma unroll
            for (int j4 = 0; j4 < 16; ++j4) {
                const float4 c = ((const float4*)crow)[j4];
                float rv, a0, q0;
                rv = rr[4*j4+0]; a0 = c.x - rv; q0 = rv + a0; rr[4*j4+0] = rv - q0; part = fmaf(a0,a0,part);
                rv = rr[4*j4+1]; a0 = c.y - rv; q0 = rv + a0; rr[4*j4+1] = rv - q0; part = fmaf(a0,a0,part);
                rv = rr[4*j4+2]; a0 = c.z - rv; q0 = rv + a0; rr[4*j4+2] = rv - q0; part = fmaf(a0,a0,part);
                rv = rr[4*j4+3]; a0 = c.w - rv; q0 = rv + a0; rr[4*j4+3] = rv - q0; part = fmaf(a0,a0,part);
            }
            #pragma unroll
            for (int off = 32; off > 0; off >>= 1) part += __shfl_down(part, off);
            if (lane == 0) lossw[w] = part;
        }
        __syncthreads();   // (6) lossw ready
        if (tid == 0) {
            float s = 0.f;
            #pragma unroll
            for (int ww = 0; ww < 8; ++ww) s += lossw[ww];
            ws[WS_PART + q * NBLK + blk] = s;
        }
    }

    // quantized_out = x - r_final
    #pragma unroll
    for (int j = 0; j < 64; ++j) {
        const size_t a = xbase + (size_t)((w << 6) + j) * T;
        out[OUT_Q + a] = x[a] - rr[j];
    }
}

// ================= fallback (round-5 verified kernel, 64 pts/block) =========
static constexpr int FB_TPB = 64;
static constexpr int FB_NBLK = N / FB_TPB;   // 750
static constexpr int KT  = 32;
static constexpr int DC  = 16;
static constexpr int KPW = 256;
static constexpr int TOPC = 3;
static constexpr float FBWIN = 3e-4f;

__global__ __launch_bounds__(NTHR) void rvq_fallback(
    const float* __restrict__ x, const float* __restrict__ cb,
    float* __restrict__ out, float* __restrict__ ws)
{
    __shared__ float r[D][FB_TPB];
    __shared__ float cbc[8][KT][DC];
    __shared__ float redv[8][TOPC][FB_TPB];
    __shared__ int   redi[8][TOPC][FB_TPB];
    __shared__ int   kstar[FB_TPB];
    __shared__ float lossw[8];

    const int tid  = threadIdx.x;
    const int w    = tid >> 6;
    const int lane = tid & 63;
    const int blk  = blockIdx.x;
    const int n0   = blk * FB_TPB;

    const int n  = n0 + lane;
    const int bp = n / T;
    const int tp = n - bp * T;
    const size_t xbase = (size_t)bp * (D * T) + tp;

    for (int j = 0; j < 64; ++j) {
        const int d = (w << 6) + j;
        r[d][lane] = x[xbase + (size_t)d * T];
    }
    __syncthreads();

    const int kw0  = w * KPW;
    const int lrow = lane >> 2;
    const int lcol = (lane & 3) << 2;

    for (int q = 0; q < NQ; ++q) {
        const float* __restrict__ cbq = cb + (size_t)q * K * D;
        const float* __restrict__ ccq = ws + WS_CC + q * K;

        float v1 = 3.0e38f, v2 = 3.0e38f, v3 = 3.0e38f;
        int   i1 = 0,       i2 = 0,       i3 = 0;
        float4 pf0, pf1;
        {
            const float* s0 = cbq + (size_t)(kw0 + lrow) * D + lcol;
            pf0 = *(const float4*)(s0);
            pf1 = *(const float4*)(s0 + 16 * D);
        }
        #pragma unroll 1
        for (int kc = 0; kc < KPW / KT; ++kc) {
            const int k0 = kw0 + kc * KT;
            float acc[KT];
            #pragma unroll
            for (int kk = 0; kk < KT; ++kk) acc[kk] = 0.f;
            #pragma unroll 1
            for (int dc = 0; dc < D / DC; ++dc) {
                asm volatile("s_waitcnt lgkmcnt(0)" ::: "memory");
                ((float4*)&cbc[w][0][0])[lane]      = pf0;
                ((float4*)&cbc[w][0][0])[lane + 64] = pf1;
                {
                    int nkc = kc, ndc = dc + 1;
                    if (ndc == D / DC) { ndc = 0; nkc++; }
                    if (nkc < KPW / KT) {
                        const float* s0 = cbq + (size_t)(kw0 + nkc * KT + lrow) * D
                                              + ndc * DC + lcol;
                        pf0 = *(const float4*)(s0);
                        pf1 = *(const float4*)(s0 + 16 * D);
                    }
                }
                asm volatile("s_waitcnt lgkmcnt(0)" ::: "memory");
                const int d0 = dc * DC;
                #pragma unroll
                for (int dd = 0; dd < DC; dd += 4) {
                    const float r0 = r[d0 + dd + 0][lane];
                    const float r1 = r[d0 + dd + 1][lane];
                    const float r2 = r[d0 + dd + 2][lane];
                    const float r3 = r[d0 + dd + 3][lane];
                    #pragma unroll
                    for (int kk = 0; kk < KT; ++kk) {
                        const float4 c = *(const float4*)&cbc[w][kk][dd];
                        acc[kk] = fmaf(c.x, r0, acc[kk]);
                        acc[kk] = fmaf(c.y, r1, acc[kk]);
                        acc[kk] = fmaf(c.z, r2, acc[kk]);
                        acc[kk] = fmaf(c.w, r3, acc[kk]);
                    }
                }
            }
            #pragma unroll
            for (int kk = 0; kk < KT; ++kk) {
                const float s = fmaf(-2.f, acc[kk], ccq[k0 + kk]);
                if (s < v1)      { v3 = v2; i3 = i2; v2 = v1; i2 = i1; v1 = s; i1 = k0 + kk; }
                else if (s < v2) { v3 = v2; i3 = i2; v2 = s;  i2 = k0 + kk; }
                else if (s < v3) { v3 = s;  i3 = k0 + kk; }
            }
        }
        redv[w][0][lane] = v1; redi[w][0][lane] = i1;
        redv[w][1][lane] = v2; redi[w][1][lane] = i2;
        redv[w][2][lane] = v3; redi[w][2][lane] = i3;
        __syncthreads();

        if (tid < FB_TPB) {
            const int p = tid;
            float C4[4];
            #pragma unroll 1
            for (int b4 = 0; b4 < 4; ++b4) {
                const int base = b4 * 128;
                float a0,a1,a2,a3,a4,a5,a6,a7;
                {
                    float t0=r[base+0][p], t1=r[base+1][p], t2=r[base+2][p], t3=r[base+3][p];
                    float t4=r[base+4][p], t5=r[base+5][p], t6=r[base+6][p], t7=r[base+7][p];
                    a0=t0*t0; a1=t1*t1; a2=t2*t2; a3=t3*t3;
                    a4=t4*t4; a5=t5*t5; a6=t6*t6; a7=t7*t7;
                }
                for (int j = 8; j < 128; j += 8) {
                    float t0=r[base+j+0][p], t1=r[base+j+1][p];
                    float t2=r[base+j+2][p], t3=r[base+j+3][p];
                    float t4=r[base+j+4][p], t5=r[base+j+5][p];
                    float t6=r[base+j+6][p], t7=r[base+j+7][p];
                    a0+=t0*t0; a1+=t1*t1; a2+=t2*t2; a3+=t3*t3;
                    a4+=t4*t4; a5+=t5*t5; a6+=t6*t6; a7+=t7*t7;
                }
                C4[b4] = ((a0+a1)+(a2+a3)) + ((a4+a5)+(a6+a7));
            }
            const float xx = (C4[0] + C4[1]) + (C4[2] + C4[3]);

            float bv = 3.0e38f;
            #pragma unroll
            for (int ww = 0; ww < 8; ++ww)
                #pragma unroll
                for (int j = 0; j < TOPC; ++j) {
                    const float v = redv[ww][j][p];
                    if (v < bv) bv = v;
                }
            float bestE = 3.0e38f; int bestK = 0x7fffffff;
            #pragma unroll 1
            for (int ww = 0; ww < 8; ++ww)
                #pragma unroll 1
                for (int j = 0; j < TOPC; ++j) {
                    const float v = redv[ww][j][p];
                    const int  kk = redi[ww][j][p];
                    if (v <= bv + FBWIN) {
                        const float* crow = cbq + (size_t)kk * D;
                        float mm = 0.f;
                        #pragma unroll 1
                        for (int d = 0; d < D; d += 4) {
                            const float4 c = *(const float4*)(crow + d);
                            mm = fmaf(c.x, r[d+0][p], mm);
                            mm = fmaf(c.y, r[d+1][p], mm);
                            mm = fmaf(c.z, r[d+2][p], mm);
                            mm = fmaf(c.w, r[d+3][p], mm);
                        }
                        const float D1 = xx - 2.0f * mm;
                        const float E  = D1 + ccq[kk];
                        if (E < bestE || (E == bestE && kk < bestK)) { bestE = E; bestK = kk; }
                    }
                }
            kstar[p] = bestK;
            const int nn = n0 + p;
            const int b2 = nn / T;
            const int t2 = nn - b2 * T;
            out[OUT_IDX + (size_t)b2 * (NQ * T) + (size_t)q * T + t2] = (float)bestK;
        }
        __syncthreads();

        {
            const int kp = kstar[lane];
            const float* __restrict__ crow = cbq + (size_t)kp * D;
            float part = 0.f;
            #pragma unroll 1
            for (int j = 0; j < 64; j += 4) {
                const int d = (w << 6) + j;
                const float4 c = *(const float4*)(crow + d);
                float rv0 = r[d + 0][lane], rv1 = r[d + 1][lane];
                float rv2 = r[d + 2][lane], rv3 = r[d + 3][lane];
                float a0 = c.x - rv0, a1 = c.y - rv1;
                float a2 = c.z - rv2, a3 = c.w - rv3;
                float q0 = rv0 + a0, q1 = rv1 + a1;
                float q2 = rv2 + a2, q3 = rv3 + a3;
                r[d + 0][lane] = rv0 - q0; r[d + 1][lane] = rv1 - q1;
                r[d + 2][lane] = rv2 - q2; r[d + 3][lane] = rv3 - q3;
                part = fmaf(a0, a0, part); part = fmaf(a1, a1, part);
                part = fmaf(a2, a2, part); part = fmaf(a3, a3, part);
            }
            #pragma unroll
            for (int off = 32; off > 0; off >>= 1) part += __shfl_down(part, off);
            if (lane == 0) lossw[w] = part;
        }
        __syncthreads();
        if (tid == 0) {
            float s = 0.f;
            #pragma unroll
            for (int ww = 0; ww < 8; ++ww) s += lossw[ww];
            ws[WS_PART + q * FB_NBLK + blk] = s;
        }
        __syncthreads();
    }

    for (int j = 0; j < 64; ++j) {
        const int d = (w << 6) + j;
        const size_t a = xbase + (size_t)d * T;
        out[OUT_Q + a] = x[a] - r[d][lane];
    }
}

// ---- deterministic loss finalize ------------------------------------------
__global__ void loss_kernel(const float* __restrict__ ws, float* __restrict__ out,
                            int npart) {
    __shared__ double s[256];
    double acc = 0.0;
    for (int i = threadIdx.x; i < npart; i += 256) acc += (double)ws[WS_PART + i];
    s[threadIdx.x] = acc;
    __syncthreads();
    for (int o = 128; o > 0; o >>= 1) {
        if ((int)threadIdx.x < o) s[threadIdx.x] += s[threadIdx.x + o];
        __syncthreads();
    }
    if (threadIdx.x == 0)
        out[OUT_LOSS] = (float)(s[0] / (double)((size_t)B * D * T));
}

extern "C" void kernel_launch(void* const* d_in, const int* in_sizes, int n_in,
                              void* d_out, int out_size, void* d_ws, size_t ws_size,
                              hipStream_t stream) {
    const float* x  = (const float*)d_in[0];
    const float* cb = (const float*)d_in[1];
    float* out = (float*)d_out;
    float* ws  = (float*)d_ws;

    hipLaunchKernelGGL(cc_kernel, dim3((NQ * K + 255) / 256), dim3(256), 0, stream, cb, ws);
    if (ws_size >= WS_NEEDED) {
        uint4* wsA = (uint4*)((char*)d_ws + WS_A_OFF);
        hipLaunchKernelGGL(prep_kernel, dim3((unsigned)(A_TILES_U4 / 256)), dim3(256),
                           0, stream, cb, wsA);
        hipLaunchKernelGGL(rvq_main, dim3(NBLK), dim3(NTHR), 0, stream, x, cb, out, ws);
        hipLaunchKernelGGL(loss_kernel, dim3(1), dim3(256), 0, stream, ws, out,
                           NQ * NBLK);
    } else {
        hipLaunchKernelGGL(rvq_fallback, dim3(FB_NBLK), dim3(NTHR), 0, stream, x, cb, out, ws);
        hipLaunchKernelGGL(loss_kernel, dim3(1), dim3(256), 0, stream, ws, out,
                           NQ * FB_NBLK);
    }
}